// Round 5
// baseline (1574.182 us; speedup 1.0000x reference)
//
#include <hip/hip_runtime.h>
#include <hip/hip_fp16.h>

#define N_NODES 100000
#define E_EDGES 3200000
#define NG      512
#define BN_EPS  1e-5f

#define BSH     7                 // 128 nodes per bucket
#define BNODES  128
#define NBUCK   782               // ceil(100000/128)
#define NCHUNK  1024
#define CHUNK   3125              // E_EDGES / NCHUNK
#define GCH     48                // gather work-steal chunk (nodes per steal)

// ---------------- zero stats / pool accumulators / steal queues ----------------
__global__ __launch_bounds__(256) void k_zero(float* __restrict__ stats1,
                                              float* __restrict__ stats2,
                                              float* __restrict__ sums,
                                              float* __restrict__ cnt,
                                              int* __restrict__ q) {
  int i = blockIdx.x * 256 + threadIdx.x;
  if (i < 128) { stats1[i] = 0.f; stats2[i] = 0.f; }
  if (i < NG * 64) sums[i] = 0.f;
  if (i < NG) cnt[i] = 0.f;
  if (i < 8) q[i] = 0;
}

// ---------------- per-chunk bucket histogram (LDS, no global atomics) ----------------
__global__ __launch_bounds__(256) void kb_hist(const int* __restrict__ ei,
                                               int* __restrict__ counts) {
  __shared__ int h[NBUCK];
  const int c = blockIdx.x, tid = threadIdx.x;
  for (int b = tid; b < NBUCK; b += 256) h[b] = 0;
  __syncthreads();
  const int* dst = ei + E_EDGES + c * CHUNK;
  for (int i = tid; i < CHUNK; i += 256) atomicAdd(&h[dst[i] >> BSH], 1);
  __syncthreads();
  for (int b = tid; b < NBUCK; b += 256) counts[b * NCHUNK + c] = h[b];
}

// ---------------- scan 1: within-bucket exclusive scan over chunks ----------------
__global__ __launch_bounds__(1024) void kb_scan1(int* __restrict__ counts,
                                                 int* __restrict__ btot) {
  __shared__ int sm[NCHUNK];
  const int b = blockIdx.x, tid = threadIdx.x;
  const int cval = counts[b * NCHUNK + tid];
  int val = cval;
  sm[tid] = val;
  __syncthreads();
  for (int off = 1; off < NCHUNK; off <<= 1) {
    int t = (tid >= off) ? sm[tid - off] : 0;
    __syncthreads();
    val += t;
    sm[tid] = val;
    __syncthreads();
  }
  counts[b * NCHUNK + tid] = val - cval;
  if (tid == NCHUNK - 1) btot[b] = val;
}

// ---------------- scan 2: exclusive scan of bucket totals ----------------
__global__ __launch_bounds__(1024) void kb_scan2(const int* __restrict__ btot,
                                                 int* __restrict__ bbase) {
  __shared__ int sm[1024];
  const int tid = threadIdx.x;
  const int cval = (tid < NBUCK) ? btot[tid] : 0;
  int val = cval;
  sm[tid] = val;
  __syncthreads();
  for (int off = 1; off < 1024; off <<= 1) {
    int t = (tid >= off) ? sm[tid - off] : 0;
    __syncthreads();
    val += t;
    sm[tid] = val;
    __syncthreads();
  }
  if (tid < NBUCK) bbase[tid] = val - cval;
  if (tid == NBUCK - 1) bbase[NBUCK] = val;  // == E_EDGES
}

// ---------------- partitioned scatter: pack (dstLocal<<17)|src into bucket runs ----------------
__global__ __launch_bounds__(256) void kb_scatter(const int* __restrict__ ei,
                                                  const int* __restrict__ counts,
                                                  const int* __restrict__ bbase,
                                                  int* __restrict__ binned) {
  __shared__ int cur[NBUCK];
  const int c = blockIdx.x, tid = threadIdx.x;
  for (int b = tid; b < NBUCK; b += 256) cur[b] = bbase[b] + counts[b * NCHUNK + c];
  __syncthreads();
  const int* srcp = ei + c * CHUNK;
  const int* dstp = ei + E_EDGES + c * CHUNK;
  for (int i = tid; i < CHUNK; i += 256) {
    const int s = srcp[i], d = dstp[i];
    const int pos = atomicAdd(&cur[d >> BSH], 1);
    binned[pos] = ((d & (BNODES - 1)) << 17) | s;
  }
}

// ---------------- per-bucket counting sort -> CSR + row_start + dis ----------------
__global__ __launch_bounds__(256) void kb_degsort(const int* __restrict__ binned,
                                                  const int* __restrict__ bbase,
                                                  int* __restrict__ csr,
                                                  int* __restrict__ row_start,
                                                  float* __restrict__ dis) {
  __shared__ int h[BNODES];    // counts, then cursors
  __shared__ int pre[BNODES];  // inclusive prefix
  const int b = blockIdx.x, tid = threadIdx.x;
  if (tid < BNODES) h[tid] = 0;
  __syncthreads();
  const int e0 = bbase[b], e1 = bbase[b + 1];
  for (int i = e0 + tid; i < e1; i += 256) atomicAdd(&h[binned[i] >> 17], 1);
  __syncthreads();
  if (tid < BNODES) pre[tid] = h[tid];
  __syncthreads();
  for (int off = 1; off < BNODES; off <<= 1) {
    int t = (tid >= off && tid < BNODES) ? pre[tid - off] : 0;
    __syncthreads();
    if (tid < BNODES) pre[tid] += t;
    __syncthreads();
  }
  if (tid < BNODES) {
    const int n = b * BNODES + tid;
    const int ex = e0 + pre[tid] - h[tid];  // exclusive start for this node
    if (n < N_NODES) {
      row_start[n] = ex;
      dis[n] = rsqrtf((float)(h[tid] + 1));  // +1 self loop
    }
    h[tid] = ex;  // cursor
  }
  if (b == NBUCK - 1 && tid == 0) row_start[N_NODES] = E_EDGES;
  __syncthreads();
  for (int i = e0 + tid; i < e1; i += 256) {
    const int v = binned[i];
    const int pos = atomicAdd(&h[v >> 17], 1);
    csr[pos] = v & 0x1FFFF;  // writes stay inside this bucket's ~16KB window
  }
}

// ---------------- GEMM: y[s][n][cl] = half(dis[n] * sum_c in'[n][c]*W[c][s*16+cl]) ----
// y is SLICE-MAJOR [4][N][16]: each 16-channel slice is a contiguous 3.2MB region.
template <int K, bool BN>
__global__ __launch_bounds__(256) void k_gemm(const float* __restrict__ in,
                                              const float* __restrict__ W,
                                              const float* __restrict__ dis,
                                              const float* __restrict__ stats,
                                              const float* __restrict__ gam,
                                              const float* __restrict__ bet,
                                              __half* __restrict__ y) {
  __shared__ float xs[64 * 68];   // [n][c] padded (stride 68)
  __shared__ float wsm[64 * 64];  // [c][ch]
  __shared__ float scv[64], shv[64];
  const int tid = threadIdx.x;
  const int n0 = blockIdx.x * 64;
  const int lane = tid & 63, wv = tid >> 6;
  const int nq = lane & 15;
  const int chb = wv * 16 + (lane >> 4) * 4;
  if (BN) {
    if (tid < 64) {
      const float m = stats[tid] * (1.0f / N_NODES);
      const float v = stats[64 + tid] * (1.0f / N_NODES) - m * m;
      const float sc = rsqrtf(v + BN_EPS) * gam[tid];
      scv[tid] = sc;
      shv[tid] = bet[tid] - m * sc;
    }
  }
  float a[4][4] = {{0,0,0,0},{0,0,0,0},{0,0,0,0},{0,0,0,0}};
  for (int c0 = 0; c0 < K; c0 += 64) {
    __syncthreads();
#pragma unroll
    for (int i = 0; i < 4; ++i) {
      const int idx = tid + i * 256;
      const int n = idx >> 4, c4 = (idx & 15) * 4;
      const int nn = min(n0 + n, N_NODES - 1);
      float4 v = *(const float4*)&in[(size_t)nn * K + c0 + c4];
      if (BN) {
        v.x = v.x * scv[c4] + shv[c4];
        v.y = v.y * scv[c4 + 1] + shv[c4 + 1];
        v.z = v.z * scv[c4 + 2] + shv[c4 + 2];
        v.w = v.w * scv[c4 + 3] + shv[c4 + 3];
      }
      *(float4*)&xs[n * 68 + c4] = v;
    }
#pragma unroll
    for (int i = 0; i < 4; ++i) {
      const int idx = tid + i * 256;
      const int c = idx >> 4, ch4 = (idx & 15) * 4;
      *(float4*)&wsm[c * 64 + ch4] = *(const float4*)&W[(size_t)(c0 + c) * 64 + ch4];
    }
    __syncthreads();
    for (int c = 0; c < 64; c += 4) {
      float wq[4][4];
#pragma unroll
      for (int cc = 0; cc < 4; ++cc) {
        const float4 w4 = *(const float4*)&wsm[(c + cc) * 64 + chb];
        wq[cc][0] = w4.x; wq[cc][1] = w4.y; wq[cc][2] = w4.z; wq[cc][3] = w4.w;
      }
#pragma unroll
      for (int i = 0; i < 4; ++i) {
        const float4 xv = *(const float4*)&xs[(nq + 16 * i) * 68 + c];
#pragma unroll
        for (int j = 0; j < 4; ++j) {
          a[i][j] = fmaf(xv.x, wq[0][j],
                    fmaf(xv.y, wq[1][j],
                    fmaf(xv.z, wq[2][j],
                    fmaf(xv.w, wq[3][j], a[i][j]))));
        }
      }
    }
  }
#pragma unroll
  for (int i = 0; i < 4; ++i) {
    const int n = n0 + nq + 16 * i;
    if (n < N_NODES) {
      const float d = dis[n];
      union { __half h[4]; float2 f; } u;
      u.h[0] = __float2half_rn(d * a[i][0]);
      u.h[1] = __float2half_rn(d * a[i][1]);
      u.h[2] = __float2half_rn(d * a[i][2]);
      u.h[3] = __float2half_rn(d * a[i][3]);
      // slice-major store: slice = wv, local col = (lane>>4)*4
      *(float2*)&y[((size_t)wv * N_NODES + n) * 16 + (lane >> 4) * 4] = u.f;
    }
  }
}

// ---------------- XCD-affine work-stealing gather over slice-major y[4][N][16] ------
// slice = (HW XCC_ID)>>1 (hardware truth via s_getreg, not blockIdx assumption).
// Node ranges come from a per-slice atomic queue (chunks of GCH nodes): exactly-once
// coverage under ANY block->XCD mapping; after draining its own slice, a wave steals
// from the other slices' queues (correctness guaranteed even if XCC read were wrong).
// csr is NT-loaded with depth-1 register prefetch: node edge ranges are contiguous,
// so the next strip base is min(pb+32, end); next-strip indices are issued before the
// current strip's y loads are consumed, hiding the ~900cy NT-HBM csr latency.
// Lane layout: slot = lane>>2 (16 edge slots), cq = lane&3 (4 fp16 via float2).
// Butterfly: +32,+16 pure adds, then channel-split levels (+8,+4); lanes<16 own
// channel ch = sbase + cq*4 + (slot&3). Stats staged in LDS (float atomics).
template <bool POOL>
__global__ __launch_bounds__(256) void k_gather(const int* __restrict__ csr,
                                                const int* __restrict__ rs,
                                                const __half* __restrict__ y,
                                                const float* __restrict__ dis,
                                                const float* __restrict__ bias,
                                                float* __restrict__ hout,
                                                float* __restrict__ stats,
                                                const int* __restrict__ batch,
                                                float* __restrict__ sums,
                                                float* __restrict__ cnt,
                                                int* __restrict__ q,
                                                const int qbase) {
  __shared__ float r1sh[64], r2sh[64];
  const int tid  = threadIdx.x;
  const int lane = tid & 63;
  const int slot = lane >> 2;            // edge slot 0..15
  const int cq   = lane & 3;             // channel quad within slice
  const int chl  = cq * 4 + (slot & 3);  // local channel this lane ends up owning
  if (tid < 64) { r1sh[tid] = 0.f; r2sh[tid] = 0.f; }
  __syncthreads();
  const int xcc = __builtin_amdgcn_s_getreg(6164) & 7;  // hwreg(HW_REG_XCC_ID=20,0,4)
  const int xslice = (xcc >> 1) & 3;
  union U4 { float2 f2; __half2 h2[2]; };
  for (int ss = 0; ss < 4; ++ss) {
    const int sl    = (xslice + ss) & 3;
    const int sbase = sl * 16;
    const int ch    = sbase + chl;
    const float bch = bias[ch];
    const __half* yb = y + (size_t)sl * N_NODES * 16 + cq * 4;
    while (true) {
      int c0;
      if (lane == 0) c0 = atomicAdd(&q[qbase + sl], GCH);
      c0 = __shfl(c0, 0);
      if (c0 >= N_NODES) break;
      const int c1 = min(N_NODES, c0 + GCH);
      // csr strip prefetch pipeline (depth 1)
      int pb  = rs[c0];
      int pfa = __builtin_nontemporal_load(&csr[min(pb + slot, E_EDGES - 1)]);
      int pfb = __builtin_nontemporal_load(&csr[min(pb + 16 + slot, E_EDGES - 1)]);
      float s1 = 0.f, s2 = 0.f;
      int curg = -1, run = 0;
      float px = 0.f;
      for (int n = c0; n < c1; ++n) {
        const int end = rs[n + 1];
        float a0 = 0.f, a1 = 0.f, a2 = 0.f, a3 = 0.f;
        if (slot == 0) {  // self-loop term
          U4 u;
          u.f2 = *(const float2*)&yb[(size_t)n * 16];
          const float2 f0 = __half22float2(u.h2[0]);
          const float2 f1 = __half22float2(u.h2[1]);
          a0 += f0.x; a1 += f0.y; a2 += f1.x; a3 += f1.y;
        }
        while (pb < end) {
          const int rem = end - pb;
          const int ca = pfa, cb = pfb;
          pb = (rem > 32) ? pb + 32 : end;  // next strip base (contiguous ranges)
          pfa = __builtin_nontemporal_load(&csr[min(pb + slot, E_EDGES - 1)]);
          pfb = __builtin_nontemporal_load(&csr[min(pb + 16 + slot, E_EDGES - 1)]);
          if (rem >= 32) {
            U4 ua, ub;
            ua.f2 = *(const float2*)&yb[(size_t)ca * 16];
            ub.f2 = *(const float2*)&yb[(size_t)cb * 16];
            const float2 fa0 = __half22float2(ua.h2[0]);
            const float2 fa1 = __half22float2(ua.h2[1]);
            const float2 fb0 = __half22float2(ub.h2[0]);
            const float2 fb1 = __half22float2(ub.h2[1]);
            a0 += fa0.x + fb0.x; a1 += fa0.y + fb0.y;
            a2 += fa1.x + fb1.x; a3 += fa1.y + fb1.y;
          } else {
            if (slot < rem) {
              U4 ua;
              ua.f2 = *(const float2*)&yb[(size_t)ca * 16];
              const float2 fa0 = __half22float2(ua.h2[0]);
              const float2 fa1 = __half22float2(ua.h2[1]);
              a0 += fa0.x; a1 += fa0.y; a2 += fa1.x; a3 += fa1.y;
            }
            if (16 + slot < rem) {
              U4 ub;
              ub.f2 = *(const float2*)&yb[(size_t)cb * 16];
              const float2 fb0 = __half22float2(ub.h2[0]);
              const float2 fb1 = __half22float2(ub.h2[1]);
              a0 += fb0.x; a1 += fb0.y; a2 += fb1.x; a3 += fb1.y;
            }
          }
        }
        // butterfly across 16 edge slots (lane bits 5..2)
        a0 += __shfl_xor(a0, 32); a1 += __shfl_xor(a1, 32);
        a2 += __shfl_xor(a2, 32); a3 += __shfl_xor(a3, 32);
        a0 += __shfl_xor(a0, 16); a1 += __shfl_xor(a1, 16);
        a2 += __shfl_xor(a2, 16); a3 += __shfl_xor(a3, 16);
        float t0, t1;
        {
          const bool hi = (slot & 2) != 0;   // split 4ch -> 2ch
          const float sd0 = hi ? a0 : a2;
          const float sd1 = hi ? a1 : a3;
          const float kp0 = hi ? a2 : a0;
          const float kp1 = hi ? a3 : a1;
          t0 = kp0 + __shfl_xor(sd0, 8);
          t1 = kp1 + __shfl_xor(sd1, 8);
        }
        float s;
        {
          const bool hi = (slot & 1) != 0;   // split 2ch -> 1ch
          const float sd = hi ? t0 : t1;
          const float kp = hi ? t1 : t0;
          s = kp + __shfl_xor(sd, 4);
        }
        const float v = fmaxf(dis[n] * s + bch, 0.f);
        if (lane < 16) {
          if (!POOL) __builtin_nontemporal_store(v, &hout[(size_t)n * 64 + ch]);
          s1 += v;
          s2 += v * v;
        }
        if (POOL) {
          const int g = batch[n];
          if (g != curg) {
            if (run) {
              if (lane < 16) atomicAdd(&sums[curg * 64 + ch], px);
              if (lane == 0 && sl == 0) atomicAdd(&cnt[curg], (float)run);
            }
            curg = g; run = 0; px = 0.f;
          }
          if (lane < 16) px += v;
          ++run;
        }
      }
      if (POOL && run) {
        if (lane < 16) atomicAdd(&sums[curg * 64 + ch], px);
        if (lane == 0 && sl == 0) atomicAdd(&cnt[curg], (float)run);
      }
      if (lane < 16) {  // stage chunk stats in LDS (slice may vary across chunks)
        atomicAdd(&r1sh[ch], s1);
        atomicAdd(&r2sh[ch], s2);
      }
    }
  }
  __syncthreads();
  if (tid < 64) {
    atomicAdd(&stats[tid], r1sh[tid]);
  } else if (tid < 128) {
    atomicAdd(&stats[64 + (tid - 64)], r2sh[tid - 64]);
  }
}

// ---------------- fused BN2-affine + 5-layer MLP head, one block per graph ----------------
__global__ __launch_bounds__(128) void k_mlp(const float* __restrict__ sums,
                                             const float* __restrict__ cnt,
                                             const float* __restrict__ stats,
                                             const float* __restrict__ gam,
                                             const float* __restrict__ bet,
                                             const float* __restrict__ fw1, const float* __restrict__ fb1,
                                             const float* __restrict__ fw2, const float* __restrict__ fb2,
                                             const float* __restrict__ fw3, const float* __restrict__ fb3,
                                             const float* __restrict__ fw4, const float* __restrict__ fb4,
                                             const float* __restrict__ ow, const float* __restrict__ ob,
                                             float* __restrict__ out) {
  __shared__ float u0[128], u1[128];
  const int g = blockIdx.x, t = threadIdx.x;
  if (t < 64) {
    const float m = stats[t] * (1.0f / N_NODES);
    const float v = stats[64 + t] * (1.0f / N_NODES) - m * m;
    const float sc = rsqrtf(v + BN_EPS) * gam[t];
    const float sh = bet[t] - m * sc;
    u0[t] = (sums[g * 64 + t] / fmaxf(cnt[g], 1.0f)) * sc + sh;  // BN affine on pooled mean
  }
  __syncthreads();
  if (t < 128) {
    float a = fb1[t];
    for (int k = 0; k < 64; ++k) a = fmaf(u0[k], fw1[k * 128 + t], a);
    u1[t] = fmaxf(a, 0.f);
  }
  __syncthreads();
  if (t < 64) {
    float a = fb2[t];
    for (int k = 0; k < 128; ++k) a = fmaf(u1[k], fw2[k * 64 + t], a);
    u0[t] = fmaxf(a, 0.f);
  }
  __syncthreads();
  if (t < 32) {
    float a = fb3[t];
    for (int k = 0; k < 64; ++k) a = fmaf(u0[k], fw3[k * 32 + t], a);
    u1[t] = fmaxf(a, 0.f);
  }
  __syncthreads();
  if (t < 16) {
    float a = fb4[t];
    for (int k = 0; k < 32; ++k) a = fmaf(u1[k], fw4[k * 16 + t], a);
    u0[t] = fmaxf(a, 0.f);
  }
  __syncthreads();
  if (t < 2) {
    float a = ob[t];
    for (int k = 0; k < 16; ++k) a = fmaf(u0[k], ow[k * 2 + t], a);
    out[g * 2 + t] = a;
  }
}

extern "C" void kernel_launch(void* const* d_in, const int* in_sizes, int n_in,
                              void* d_out, int out_size, void* d_ws, size_t ws_size,
                              hipStream_t stream) {
  const float* x    = (const float*)d_in[0];
  const int*   ei   = (const int*)d_in[1];
  const int*   batch= (const int*)d_in[2];
  const float* w1   = (const float*)d_in[3];
  const float* b1   = (const float*)d_in[4];
  const float* w2   = (const float*)d_in[5];
  const float* b2   = (const float*)d_in[6];
  const float* g1   = (const float*)d_in[7];
  const float* be1  = (const float*)d_in[8];
  const float* g2   = (const float*)d_in[9];
  const float* be2  = (const float*)d_in[10];
  const float* fw1  = (const float*)d_in[11]; const float* fb1 = (const float*)d_in[12];
  const float* fw2  = (const float*)d_in[13]; const float* fb2 = (const float*)d_in[14];
  const float* fw3  = (const float*)d_in[15]; const float* fb3 = (const float*)d_in[16];
  const float* fw4  = (const float*)d_in[17]; const float* fb4 = (const float*)d_in[18];
  const float* ow   = (const float*)d_in[19]; const float* ob  = (const float*)d_in[20];
  float* out = (float*)d_out;

  char* ws = (char*)d_ws;
  auto alloc = [&](size_t bytes) {
    void* p = ws;
    ws += (bytes + 255) & ~(size_t)255;
    return p;
  };
  float*  dis      = (float*)alloc((size_t)N_NODES * 4);
  int*    counts   = (int*)  alloc((size_t)NBUCK * NCHUNK * 4);
  int*    btot     = (int*)  alloc((size_t)NBUCK * 4);
  int*    bbase    = (int*)  alloc((size_t)(NBUCK + 1) * 4);
  int*    binned   = (int*)  alloc((size_t)E_EDGES * 4);
  int*    csr      = (int*)  alloc((size_t)E_EDGES * 4);
  int*    row_start= (int*)  alloc((size_t)(N_NODES + 1) * 4);
  __half* yH       = (__half*)alloc((size_t)N_NODES * 64 * 2);
  float*  hB       = (float*)alloc((size_t)N_NODES * 64 * 4);
  float*  stats1   = (float*)alloc(512);
  float*  stats2   = (float*)alloc(512);
  float*  sums     = (float*)alloc((size_t)NG * 64 * 4);
  float*  cnt      = (float*)alloc((size_t)NG * 4);
  int*    q        = (int*)  alloc(32);

  const int nblkG = (N_NODES + 63) / 64;

  // zero accumulators; build node-sorted CSR via bucket binning (shared by both layers)
  k_zero    <<<128, 256, 0, stream>>>(stats1, stats2, sums, cnt, q);
  kb_hist   <<<NCHUNK, 256, 0, stream>>>(ei, counts);
  kb_scan1  <<<NBUCK, NCHUNK, 0, stream>>>(counts, btot);
  kb_scan2  <<<1, 1024, 0, stream>>>(btot, bbase);
  kb_scatter<<<NCHUNK, 256, 0, stream>>>(ei, counts, bbase, binned);
  kb_degsort<<<NBUCK, 256, 0, stream>>>(binned, bbase, csr, row_start, dis);

  // conv1: y1 = half(dis*(x@w1)) -> yH (slice-major); gather(store) -> h1raw=hB + stats1
  k_gemm<256, false><<<nblkG, 256, 0, stream>>>(x, w1, dis, nullptr, nullptr, nullptr, yH);
  k_gather<false><<<2048, 256, 0, stream>>>(csr, row_start, yH, dis, b1, hB, stats1,
                                            nullptr, nullptr, nullptr, q, 0);

  // conv2: y2 = half(dis*(BN1(h1raw)@w2)) -> yH; gather(pool) -> sums/cnt + stats2
  k_gemm<64, true><<<nblkG, 256, 0, stream>>>(hB, w2, dis, stats1, g1, be1, yH);
  k_gather<true><<<2048, 256, 0, stream>>>(csr, row_start, yH, dis, b2, nullptr, stats2,
                                           batch, sums, cnt, q, 4);

  // BN2-affine on pooled means + MLP head
  k_mlp<<<NG, 128, 0, stream>>>(sums, cnt, stats2, g2, be2,
                                fw1, fb1, fw2, fb2, fw3, fb3, fw4, fb4, ow, ob, out);
}

// Round 6
// 647.921 us; speedup vs baseline: 2.4296x; 2.4296x over previous
//
#include <hip/hip_runtime.h>
#include <hip/hip_fp16.h>

#define N_NODES 100000
#define E_EDGES 3200000
#define NG      512
#define BN_EPS  1e-5f

#define BSH     7                 // 128 nodes per bucket
#define BNODES  128
#define NBUCK   782               // ceil(100000/128)
#define NCHUNK  1024
#define CHUNK   3125              // E_EDGES / NCHUNK

// ---------------- zero stats / pool accumulators ----------------
__global__ __launch_bounds__(256) void k_zero(float* __restrict__ stats1,
                                              float* __restrict__ stats2,
                                              float* __restrict__ sums,
                                              float* __restrict__ cnt) {
  int i = blockIdx.x * 256 + threadIdx.x;
  if (i < 128) { stats1[i] = 0.f; stats2[i] = 0.f; }
  if (i < NG * 64) sums[i] = 0.f;
  if (i < NG) cnt[i] = 0.f;
}

// ---------------- per-chunk bucket histogram (LDS, no global atomics) ----------------
__global__ __launch_bounds__(256) void kb_hist(const int* __restrict__ ei,
                                               int* __restrict__ counts) {
  __shared__ int h[NBUCK];
  const int c = blockIdx.x, tid = threadIdx.x;
  for (int b = tid; b < NBUCK; b += 256) h[b] = 0;
  __syncthreads();
  const int* dst = ei + E_EDGES + c * CHUNK;
  for (int i = tid; i < CHUNK; i += 256) atomicAdd(&h[dst[i] >> BSH], 1);
  __syncthreads();
  for (int b = tid; b < NBUCK; b += 256) counts[b * NCHUNK + c] = h[b];
}

// ---------------- scan 1: within-bucket exclusive scan over chunks ----------------
__global__ __launch_bounds__(1024) void kb_scan1(int* __restrict__ counts,
                                                 int* __restrict__ btot) {
  __shared__ int sm[NCHUNK];
  const int b = blockIdx.x, tid = threadIdx.x;
  const int cval = counts[b * NCHUNK + tid];
  int val = cval;
  sm[tid] = val;
  __syncthreads();
  for (int off = 1; off < NCHUNK; off <<= 1) {
    int t = (tid >= off) ? sm[tid - off] : 0;
    __syncthreads();
    val += t;
    sm[tid] = val;
    __syncthreads();
  }
  counts[b * NCHUNK + tid] = val - cval;
  if (tid == NCHUNK - 1) btot[b] = val;
}

// ---------------- scan 2: exclusive scan of bucket totals ----------------
__global__ __launch_bounds__(1024) void kb_scan2(const int* __restrict__ btot,
                                                 int* __restrict__ bbase) {
  __shared__ int sm[1024];
  const int tid = threadIdx.x;
  const int cval = (tid < NBUCK) ? btot[tid] : 0;
  int val = cval;
  sm[tid] = val;
  __syncthreads();
  for (int off = 1; off < 1024; off <<= 1) {
    int t = (tid >= off) ? sm[tid - off] : 0;
    __syncthreads();
    val += t;
    sm[tid] = val;
    __syncthreads();
  }
  if (tid < NBUCK) bbase[tid] = val - cval;
  if (tid == NBUCK - 1) bbase[NBUCK] = val;  // == E_EDGES
}

// ---------------- partitioned scatter: pack (dstLocal<<17)|src into bucket runs ----------------
__global__ __launch_bounds__(256) void kb_scatter(const int* __restrict__ ei,
                                                  const int* __restrict__ counts,
                                                  const int* __restrict__ bbase,
                                                  int* __restrict__ binned) {
  __shared__ int cur[NBUCK];
  const int c = blockIdx.x, tid = threadIdx.x;
  for (int b = tid; b < NBUCK; b += 256) cur[b] = bbase[b] + counts[b * NCHUNK + c];
  __syncthreads();
  const int* srcp = ei + c * CHUNK;
  const int* dstp = ei + E_EDGES + c * CHUNK;
  for (int i = tid; i < CHUNK; i += 256) {
    const int s = srcp[i], d = dstp[i];
    const int pos = atomicAdd(&cur[d >> BSH], 1);
    binned[pos] = ((d & (BNODES - 1)) << 17) | s;
  }
}

// ---------------- per-bucket counting sort -> CSR + row_start + dis ----------------
__global__ __launch_bounds__(256) void kb_degsort(const int* __restrict__ binned,
                                                  const int* __restrict__ bbase,
                                                  int* __restrict__ csr,
                                                  int* __restrict__ row_start,
                                                  float* __restrict__ dis) {
  __shared__ int h[BNODES];    // counts, then cursors
  __shared__ int pre[BNODES];  // inclusive prefix
  const int b = blockIdx.x, tid = threadIdx.x;
  if (tid < BNODES) h[tid] = 0;
  __syncthreads();
  const int e0 = bbase[b], e1 = bbase[b + 1];
  for (int i = e0 + tid; i < e1; i += 256) atomicAdd(&h[binned[i] >> 17], 1);
  __syncthreads();
  if (tid < BNODES) pre[tid] = h[tid];
  __syncthreads();
  for (int off = 1; off < BNODES; off <<= 1) {
    int t = (tid >= off && tid < BNODES) ? pre[tid - off] : 0;
    __syncthreads();
    if (tid < BNODES) pre[tid] += t;
    __syncthreads();
  }
  if (tid < BNODES) {
    const int n = b * BNODES + tid;
    const int ex = e0 + pre[tid] - h[tid];  // exclusive start for this node
    if (n < N_NODES) {
      row_start[n] = ex;
      dis[n] = rsqrtf((float)(h[tid] + 1));  // +1 self loop
    }
    h[tid] = ex;  // cursor
  }
  if (b == NBUCK - 1 && tid == 0) row_start[N_NODES] = E_EDGES;
  __syncthreads();
  for (int i = e0 + tid; i < e1; i += 256) {
    const int v = binned[i];
    const int pos = atomicAdd(&h[v >> 17], 1);
    csr[pos] = v & 0x1FFFF;  // writes stay inside this bucket's ~16KB window
  }
}

// ---------------- GEMM: y[n][h] = half(dis[n] * sum_c in'[n][c]*W[c][h]) --------------
template <int K, bool BN>
__global__ __launch_bounds__(256) void k_gemm(const float* __restrict__ in,
                                              const float* __restrict__ W,
                                              const float* __restrict__ dis,
                                              const float* __restrict__ stats,
                                              const float* __restrict__ gam,
                                              const float* __restrict__ bet,
                                              __half* __restrict__ y) {
  __shared__ float xs[64 * 68];   // [n][c] padded (stride 68)
  __shared__ float wsm[64 * 64];  // [c][ch]
  __shared__ float scv[64], shv[64];
  const int tid = threadIdx.x;
  const int n0 = blockIdx.x * 64;
  const int lane = tid & 63, wv = tid >> 6;
  const int nq = lane & 15;
  const int chb = wv * 16 + (lane >> 4) * 4;
  if (BN) {
    if (tid < 64) {
      const float m = stats[tid] * (1.0f / N_NODES);
      const float v = stats[64 + tid] * (1.0f / N_NODES) - m * m;
      const float sc = rsqrtf(v + BN_EPS) * gam[tid];
      scv[tid] = sc;
      shv[tid] = bet[tid] - m * sc;
    }
  }
  float a[4][4] = {{0,0,0,0},{0,0,0,0},{0,0,0,0},{0,0,0,0}};
  for (int c0 = 0; c0 < K; c0 += 64) {
    __syncthreads();
#pragma unroll
    for (int i = 0; i < 4; ++i) {
      const int idx = tid + i * 256;
      const int n = idx >> 4, c4 = (idx & 15) * 4;
      const int nn = min(n0 + n, N_NODES - 1);
      float4 v = *(const float4*)&in[(size_t)nn * K + c0 + c4];
      if (BN) {
        v.x = v.x * scv[c4] + shv[c4];
        v.y = v.y * scv[c4 + 1] + shv[c4 + 1];
        v.z = v.z * scv[c4 + 2] + shv[c4 + 2];
        v.w = v.w * scv[c4 + 3] + shv[c4 + 3];
      }
      *(float4*)&xs[n * 68 + c4] = v;
    }
#pragma unroll
    for (int i = 0; i < 4; ++i) {
      const int idx = tid + i * 256;
      const int c = idx >> 4, ch4 = (idx & 15) * 4;
      *(float4*)&wsm[c * 64 + ch4] = *(const float4*)&W[(size_t)(c0 + c) * 64 + ch4];
    }
    __syncthreads();
    for (int c = 0; c < 64; c += 4) {
      float wq[4][4];
#pragma unroll
      for (int cc = 0; cc < 4; ++cc) {
        const float4 w4 = *(const float4*)&wsm[(c + cc) * 64 + chb];
        wq[cc][0] = w4.x; wq[cc][1] = w4.y; wq[cc][2] = w4.z; wq[cc][3] = w4.w;
      }
#pragma unroll
      for (int i = 0; i < 4; ++i) {
        const float4 xv = *(const float4*)&xs[(nq + 16 * i) * 68 + c];
#pragma unroll
        for (int j = 0; j < 4; ++j) {
          a[i][j] = fmaf(xv.x, wq[0][j],
                    fmaf(xv.y, wq[1][j],
                    fmaf(xv.z, wq[2][j],
                    fmaf(xv.w, wq[3][j], a[i][j]))));
        }
      }
    }
  }
#pragma unroll
  for (int i = 0; i < 4; ++i) {
    const int n = n0 + nq + 16 * i;
    if (n < N_NODES) {
      const float d = dis[n];
      union { __half h[4]; float2 f; } u;
      u.h[0] = __float2half_rn(d * a[i][0]);
      u.h[1] = __float2half_rn(d * a[i][1]);
      u.h[2] = __float2half_rn(d * a[i][2]);
      u.h[3] = __float2half_rn(d * a[i][3]);
      *(float2*)&y[(size_t)n * 64 + chb] = u.f;
    }
  }
}

// ---------------- wide-load gather (round-1 structure, deepened pipeline) -------------
// Lane layout: p = lane>>3 (edge slot 0..7), c8 = lane&7 (8-fp16 channel group,
// float4 = 16B/lane). One wave VMEM instr covers 8 edges x 128B = 1KB.
// Main loop: 32-edge strips -> 4 independent y-line loads in flight per lane
// (2x round-1's depth; attacks the measured latency-bound regime: 19cy/line/CU at
// only 2 lines in flight). 16/8/masked-tail ladder covers Poisson(32) degrees.
// Butterfly (3 levels: +8 pure, then channel-split +16/+32... as round 1) ends with
// each of the 64 lanes owning one channel ch = c8*8 + 4p0 + 2p1 + p2 (bijective).
template <bool POOL>
__global__ __launch_bounds__(256) void k_gather(const int* __restrict__ csr,
                                                const int* __restrict__ rs,
                                                const __half* __restrict__ y,
                                                const float* __restrict__ dis,
                                                const float* __restrict__ bias,
                                                float* __restrict__ hout,
                                                float* __restrict__ stats,
                                                const int* __restrict__ batch,
                                                float* __restrict__ sums,
                                                float* __restrict__ cnt) {
  const int tid = threadIdx.x;
  const int lane = tid & 63;
  const int p = lane >> 3;        // edge slot 0..7 within a strip
  const int c8 = lane & 7;        // channel group: channels c8*8 .. c8*8+7
  const int ch = c8 * 8 + ((p & 1) << 2) + (p & 2) + ((p >> 2) & 1);
  const int wid = (blockIdx.x * 256 + tid) >> 6;
  const int nw = (gridDim.x * 256) >> 6;
  const int per = (N_NODES + nw - 1) / nw;
  const int n0 = wid * per;
  const int n1 = min(N_NODES, n0 + per);
  const float bch = bias[ch];
  float s1 = 0.f, s2 = 0.f;
  int curg = -1, run = 0;
  float px = 0.f;
  union U8 { float4 f4; __half2 h2[4]; };
  for (int n = n0; n < n1; ++n) {
    int e = rs[n];
    const int end = rs[n + 1];
    float acc[8] = {0.f, 0.f, 0.f, 0.f, 0.f, 0.f, 0.f, 0.f};
    if (p == 0) {  // self-loop term, counted once per channel by the p==0 slot
      U8 u;
      u.f4 = *(const float4*)&y[(size_t)n * 64 + c8 * 8];
#pragma unroll
      for (int k = 0; k < 4; ++k) {
        const float2 f = __half22float2(u.h2[k]);
        acc[2 * k] += f.x;
        acc[2 * k + 1] += f.y;
      }
    }
    // main: 32 edges / iteration = 4 x 1KB y-loads in flight
    for (; e + 32 <= end; e += 32) {
      const int i0 = csr[e + p];
      const int i1 = csr[e + 8 + p];
      const int i2 = csr[e + 16 + p];
      const int i3 = csr[e + 24 + p];
      U8 u0, u1, u2, u3;
      u0.f4 = *(const float4*)&y[(size_t)i0 * 64 + c8 * 8];
      u1.f4 = *(const float4*)&y[(size_t)i1 * 64 + c8 * 8];
      u2.f4 = *(const float4*)&y[(size_t)i2 * 64 + c8 * 8];
      u3.f4 = *(const float4*)&y[(size_t)i3 * 64 + c8 * 8];
#pragma unroll
      for (int k = 0; k < 4; ++k) {
        const float2 f0 = __half22float2(u0.h2[k]);
        const float2 f1 = __half22float2(u1.h2[k]);
        const float2 f2 = __half22float2(u2.h2[k]);
        const float2 f3 = __half22float2(u3.h2[k]);
        acc[2 * k] += (f0.x + f1.x) + (f2.x + f3.x);
        acc[2 * k + 1] += (f0.y + f1.y) + (f2.y + f3.y);
      }
    }
    for (; e + 16 <= end; e += 16) {
      const int i0 = csr[e + p];
      const int i1 = csr[e + 8 + p];
      U8 u0, u1;
      u0.f4 = *(const float4*)&y[(size_t)i0 * 64 + c8 * 8];
      u1.f4 = *(const float4*)&y[(size_t)i1 * 64 + c8 * 8];
#pragma unroll
      for (int k = 0; k < 4; ++k) {
        const float2 f0 = __half22float2(u0.h2[k]);
        const float2 f1 = __half22float2(u1.h2[k]);
        acc[2 * k] += f0.x + f1.x;
        acc[2 * k + 1] += f0.y + f1.y;
      }
    }
    for (; e + 8 <= end; e += 8) {
      const int i0 = csr[e + p];
      U8 u0;
      u0.f4 = *(const float4*)&y[(size_t)i0 * 64 + c8 * 8];
#pragma unroll
      for (int k = 0; k < 4; ++k) {
        const float2 f0 = __half22float2(u0.h2[k]);
        acc[2 * k] += f0.x;
        acc[2 * k + 1] += f0.y;
      }
    }
    if (e < end) {  // tail: 1..7 edges, slots p >= rem masked
      const int rem = end - e;
      const int i0 = csr[(p < rem) ? e + p : e];
      U8 u;
      u.f4 = *(const float4*)&y[(size_t)i0 * 64 + c8 * 8];
      if (p < rem) {
#pragma unroll
        for (int k = 0; k < 4; ++k) {
          const float2 f = __half22float2(u.h2[k]);
          acc[2 * k] += f.x;
          acc[2 * k + 1] += f.y;
        }
      }
    }
    // recursive-halving butterfly across the 8 edge slots: 7 shuffles, 7 adds
    float t[4];
#pragma unroll
    for (int j = 0; j < 4; ++j) {
      const float send = (p & 1) ? acc[j] : acc[4 + j];
      const float keep = (p & 1) ? acc[4 + j] : acc[j];
      t[j] = keep + __shfl_xor(send, 8);
    }
    float u2v[2];
#pragma unroll
    for (int j = 0; j < 2; ++j) {
      const float send = (p & 2) ? t[j] : t[2 + j];
      const float keep = (p & 2) ? t[2 + j] : t[j];
      u2v[j] = keep + __shfl_xor(send, 16);
    }
    const float send3 = (p & 4) ? u2v[0] : u2v[1];
    const float keep3 = (p & 4) ? u2v[1] : u2v[0];
    const float s = keep3 + __shfl_xor(send3, 32);
    // s = full sum for channel `ch` of node n
    const float v = fmaxf(dis[n] * s + bch, 0.f);
    if (!POOL) hout[(size_t)n * 64 + ch] = v;
    s1 += v;
    s2 += v * v;
    if (POOL) {
      const int g = batch[n];
      if (g != curg) {
        if (run) {
          atomicAdd(&sums[curg * 64 + ch], px);
          if (lane == 0) atomicAdd(&cnt[curg], (float)run);
        }
        curg = g; run = 0; px = 0.f;
      }
      px += v;
      ++run;
    }
  }
  if (POOL && run) {
    atomicAdd(&sums[curg * 64 + ch], px);
    if (lane == 0) atomicAdd(&cnt[curg], (float)run);
  }
  __shared__ float r1[256], r2[256];
  const int wv = tid >> 6;
  r1[wv * 64 + ch] = s1;
  r2[wv * 64 + ch] = s2;
  __syncthreads();
  if (tid < 64) {
    atomicAdd(&stats[tid], r1[tid] + r1[tid + 64] + r1[tid + 128] + r1[tid + 192]);
  } else if (tid < 128) {
    const int h = tid - 64;
    atomicAdd(&stats[64 + h], r2[h] + r2[h + 64] + r2[h + 128] + r2[h + 192]);
  }
}

// ---------------- fused BN2-affine + 5-layer MLP head, one block per graph ----------------
__global__ __launch_bounds__(128) void k_mlp(const float* __restrict__ sums,
                                             const float* __restrict__ cnt,
                                             const float* __restrict__ stats,
                                             const float* __restrict__ gam,
                                             const float* __restrict__ bet,
                                             const float* __restrict__ fw1, const float* __restrict__ fb1,
                                             const float* __restrict__ fw2, const float* __restrict__ fb2,
                                             const float* __restrict__ fw3, const float* __restrict__ fb3,
                                             const float* __restrict__ fw4, const float* __restrict__ fb4,
                                             const float* __restrict__ ow, const float* __restrict__ ob,
                                             float* __restrict__ out) {
  __shared__ float u0[128], u1[128];
  const int g = blockIdx.x, t = threadIdx.x;
  if (t < 64) {
    const float m = stats[t] * (1.0f / N_NODES);
    const float v = stats[64 + t] * (1.0f / N_NODES) - m * m;
    const float sc = rsqrtf(v + BN_EPS) * gam[t];
    const float sh = bet[t] - m * sc;
    u0[t] = (sums[g * 64 + t] / fmaxf(cnt[g], 1.0f)) * sc + sh;  // BN affine on pooled mean
  }
  __syncthreads();
  if (t < 128) {
    float a = fb1[t];
    for (int k = 0; k < 64; ++k) a = fmaf(u0[k], fw1[k * 128 + t], a);
    u1[t] = fmaxf(a, 0.f);
  }
  __syncthreads();
  if (t < 64) {
    float a = fb2[t];
    for (int k = 0; k < 128; ++k) a = fmaf(u1[k], fw2[k * 64 + t], a);
    u0[t] = fmaxf(a, 0.f);
  }
  __syncthreads();
  if (t < 32) {
    float a = fb3[t];
    for (int k = 0; k < 64; ++k) a = fmaf(u0[k], fw3[k * 32 + t], a);
    u1[t] = fmaxf(a, 0.f);
  }
  __syncthreads();
  if (t < 16) {
    float a = fb4[t];
    for (int k = 0; k < 32; ++k) a = fmaf(u1[k], fw4[k * 16 + t], a);
    u0[t] = fmaxf(a, 0.f);
  }
  __syncthreads();
  if (t < 2) {
    float a = ob[t];
    for (int k = 0; k < 16; ++k) a = fmaf(u0[k], ow[k * 2 + t], a);
    out[g * 2 + t] = a;
  }
}

extern "C" void kernel_launch(void* const* d_in, const int* in_sizes, int n_in,
                              void* d_out, int out_size, void* d_ws, size_t ws_size,
                              hipStream_t stream) {
  const float* x    = (const float*)d_in[0];
  const int*   ei   = (const int*)d_in[1];
  const int*   batch= (const int*)d_in[2];
  const float* w1   = (const float*)d_in[3];
  const float* b1   = (const float*)d_in[4];
  const float* w2   = (const float*)d_in[5];
  const float* b2   = (const float*)d_in[6];
  const float* g1   = (const float*)d_in[7];
  const float* be1  = (const float*)d_in[8];
  const float* g2   = (const float*)d_in[9];
  const float* be2  = (const float*)d_in[10];
  const float* fw1  = (const float*)d_in[11]; const float* fb1 = (const float*)d_in[12];
  const float* fw2  = (const float*)d_in[13]; const float* fb2 = (const float*)d_in[14];
  const float* fw3  = (const float*)d_in[15]; const float* fb3 = (const float*)d_in[16];
  const float* fw4  = (const float*)d_in[17]; const float* fb4 = (const float*)d_in[18];
  const float* ow   = (const float*)d_in[19]; const float* ob  = (const float*)d_in[20];
  float* out = (float*)d_out;

  char* ws = (char*)d_ws;
  auto alloc = [&](size_t bytes) {
    void* p = ws;
    ws += (bytes + 255) & ~(size_t)255;
    return p;
  };
  float*  dis      = (float*)alloc((size_t)N_NODES * 4);
  int*    counts   = (int*)  alloc((size_t)NBUCK * NCHUNK * 4);
  int*    btot     = (int*)  alloc((size_t)NBUCK * 4);
  int*    bbase    = (int*)  alloc((size_t)(NBUCK + 1) * 4);
  int*    binned   = (int*)  alloc((size_t)E_EDGES * 4);
  int*    csr      = (int*)  alloc((size_t)E_EDGES * 4);
  int*    row_start= (int*)  alloc((size_t)(N_NODES + 1) * 4);
  __half* yH       = (__half*)alloc((size_t)N_NODES * 64 * 2);
  float*  hB       = (float*)alloc((size_t)N_NODES * 64 * 4);
  float*  stats1   = (float*)alloc(512);
  float*  stats2   = (float*)alloc(512);
  float*  sums     = (float*)alloc((size_t)NG * 64 * 4);
  float*  cnt      = (float*)alloc((size_t)NG * 4);

  const int nblkG = (N_NODES + 63) / 64;

  // zero accumulators; build node-sorted CSR via bucket binning (shared by both layers)
  k_zero    <<<128, 256, 0, stream>>>(stats1, stats2, sums, cnt);
  kb_hist   <<<NCHUNK, 256, 0, stream>>>(ei, counts);
  kb_scan1  <<<NBUCK, NCHUNK, 0, stream>>>(counts, btot);
  kb_scan2  <<<1, 1024, 0, stream>>>(btot, bbase);
  kb_scatter<<<NCHUNK, 256, 0, stream>>>(ei, counts, bbase, binned);
  kb_degsort<<<NBUCK, 256, 0, stream>>>(binned, bbase, csr, row_start, dis);

  // conv1: y1 = half(dis*(x@w1)) -> yH; gather(store) -> h1raw=hB + stats1
  k_gemm<256, false><<<nblkG, 256, 0, stream>>>(x, w1, dis, nullptr, nullptr, nullptr, yH);
  k_gather<false><<<4096, 256, 0, stream>>>(csr, row_start, yH, dis, b1, hB, stats1,
                                            nullptr, nullptr, nullptr);

  // conv2: y2 = half(dis*(BN1(h1raw)@w2)) -> yH; gather(pool) -> sums/cnt + stats2
  k_gemm<64, true><<<nblkG, 256, 0, stream>>>(hB, w2, dis, stats1, g1, be1, yH);
  k_gather<true><<<4096, 256, 0, stream>>>(csr, row_start, yH, dis, b2, nullptr, stats2,
                                           batch, sums, cnt);

  // BN2-affine on pooled means + MLP head
  k_mlp<<<NG, 128, 0, stream>>>(sums, cnt, stats2, g2, be2,
                                fw1, fb1, fw2, fb2, fw3, fb3, fw4, fb4, ow, ob, out);
}

// Round 7
// 564.080 us; speedup vs baseline: 2.7907x; 1.1486x over previous
//
#include <hip/hip_runtime.h>
#include <hip/hip_fp16.h>

#define N_NODES 100000
#define E_EDGES 3200000
#define NG      512
#define BN_EPS  1e-5f

#define BSH     7                 // 128 nodes per bucket
#define BNODES  128
#define NBUCK   782               // ceil(100000/128)
#define NCHUNK  1024
#define CHUNK   3125              // E_EDGES / NCHUNK

// ---------------- zero stats / pool accumulators ----------------
__global__ __launch_bounds__(256) void k_zero(float* __restrict__ stats1,
                                              float* __restrict__ stats2,
                                              float* __restrict__ sums,
                                              float* __restrict__ cnt) {
  int i = blockIdx.x * 256 + threadIdx.x;
  if (i < 128) { stats1[i] = 0.f; stats2[i] = 0.f; }
  if (i < NG * 64) sums[i] = 0.f;
  if (i < NG) cnt[i] = 0.f;
}

// ---------------- per-chunk bucket histogram (LDS, no global atomics) ----------------
__global__ __launch_bounds__(256) void kb_hist(const int* __restrict__ ei,
                                               int* __restrict__ counts) {
  __shared__ int h[NBUCK];
  const int c = blockIdx.x, tid = threadIdx.x;
  for (int b = tid; b < NBUCK; b += 256) h[b] = 0;
  __syncthreads();
  const int* dst = ei + E_EDGES + c * CHUNK;
  for (int i = tid; i < CHUNK; i += 256) atomicAdd(&h[dst[i] >> BSH], 1);
  __syncthreads();
  for (int b = tid; b < NBUCK; b += 256) counts[b * NCHUNK + c] = h[b];
}

// ---------------- scan 1: within-bucket exclusive scan over chunks ----------------
__global__ __launch_bounds__(1024) void kb_scan1(int* __restrict__ counts,
                                                 int* __restrict__ btot) {
  __shared__ int sm[NCHUNK];
  const int b = blockIdx.x, tid = threadIdx.x;
  const int cval = counts[b * NCHUNK + tid];
  int val = cval;
  sm[tid] = val;
  __syncthreads();
  for (int off = 1; off < NCHUNK; off <<= 1) {
    int t = (tid >= off) ? sm[tid - off] : 0;
    __syncthreads();
    val += t;
    sm[tid] = val;
    __syncthreads();
  }
  counts[b * NCHUNK + tid] = val - cval;
  if (tid == NCHUNK - 1) btot[b] = val;
}

// ---------------- scan 2: exclusive scan of bucket totals ----------------
__global__ __launch_bounds__(1024) void kb_scan2(const int* __restrict__ btot,
                                                 int* __restrict__ bbase) {
  __shared__ int sm[1024];
  const int tid = threadIdx.x;
  const int cval = (tid < NBUCK) ? btot[tid] : 0;
  int val = cval;
  sm[tid] = val;
  __syncthreads();
  for (int off = 1; off < 1024; off <<= 1) {
    int t = (tid >= off) ? sm[tid - off] : 0;
    __syncthreads();
    val += t;
    sm[tid] = val;
    __syncthreads();
  }
  if (tid < NBUCK) bbase[tid] = val - cval;
  if (tid == NBUCK - 1) bbase[NBUCK] = val;  // == E_EDGES
}

// ---------------- partitioned scatter: pack (dstLocal<<17)|src into bucket runs ----------------
__global__ __launch_bounds__(256) void kb_scatter(const int* __restrict__ ei,
                                                  const int* __restrict__ counts,
                                                  const int* __restrict__ bbase,
                                                  int* __restrict__ binned) {
  __shared__ int cur[NBUCK];
  const int c = blockIdx.x, tid = threadIdx.x;
  for (int b = tid; b < NBUCK; b += 256) cur[b] = bbase[b] + counts[b * NCHUNK + c];
  __syncthreads();
  const int* srcp = ei + c * CHUNK;
  const int* dstp = ei + E_EDGES + c * CHUNK;
  for (int i = tid; i < CHUNK; i += 256) {
    const int s = srcp[i], d = dstp[i];
    const int pos = atomicAdd(&cur[d >> BSH], 1);
    binned[pos] = ((d & (BNODES - 1)) << 17) | s;
  }
}

// ---------------- per-bucket counting sort -> CSR + row_start + dis ----------------
__global__ __launch_bounds__(256) void kb_degsort(const int* __restrict__ binned,
                                                  const int* __restrict__ bbase,
                                                  int* __restrict__ csr,
                                                  int* __restrict__ row_start,
                                                  float* __restrict__ dis) {
  __shared__ int h[BNODES];    // counts, then cursors
  __shared__ int pre[BNODES];  // inclusive prefix
  const int b = blockIdx.x, tid = threadIdx.x;
  if (tid < BNODES) h[tid] = 0;
  __syncthreads();
  const int e0 = bbase[b], e1 = bbase[b + 1];
  for (int i = e0 + tid; i < e1; i += 256) atomicAdd(&h[binned[i] >> 17], 1);
  __syncthreads();
  if (tid < BNODES) pre[tid] = h[tid];
  __syncthreads();
  for (int off = 1; off < BNODES; off <<= 1) {
    int t = (tid >= off && tid < BNODES) ? pre[tid - off] : 0;
    __syncthreads();
    if (tid < BNODES) pre[tid] += t;
    __syncthreads();
  }
  if (tid < BNODES) {
    const int n = b * BNODES + tid;
    const int ex = e0 + pre[tid] - h[tid];  // exclusive start for this node
    if (n < N_NODES) {
      row_start[n] = ex;
      dis[n] = rsqrtf((float)(h[tid] + 1));  // +1 self loop
    }
    h[tid] = ex;  // cursor
  }
  if (b == NBUCK - 1 && tid == 0) row_start[N_NODES] = E_EDGES;
  __syncthreads();
  for (int i = e0 + tid; i < e1; i += 256) {
    const int v = binned[i];
    const int pos = atomicAdd(&h[v >> 17], 1);
    csr[pos] = v & 0x1FFFF;  // writes stay inside this bucket's ~16KB window
  }
}

// ---------------- GEMM: y[n][h] = half(dis[n] * sum_c in'[n][c]*W[c][h]) --------------
template <int K, bool BN>
__global__ __launch_bounds__(256) void k_gemm(const float* __restrict__ in,
                                              const float* __restrict__ W,
                                              const float* __restrict__ dis,
                                              const float* __restrict__ stats,
                                              const float* __restrict__ gam,
                                              const float* __restrict__ bet,
                                              __half* __restrict__ y) {
  __shared__ float xs[64 * 68];   // [n][c] padded (stride 68)
  __shared__ float wsm[64 * 64];  // [c][ch]
  __shared__ float scv[64], shv[64];
  const int tid = threadIdx.x;
  const int n0 = blockIdx.x * 64;
  const int lane = tid & 63, wv = tid >> 6;
  const int nq = lane & 15;
  const int chb = wv * 16 + (lane >> 4) * 4;
  if (BN) {
    if (tid < 64) {
      const float m = stats[tid] * (1.0f / N_NODES);
      const float v = stats[64 + tid] * (1.0f / N_NODES) - m * m;
      const float sc = rsqrtf(v + BN_EPS) * gam[tid];
      scv[tid] = sc;
      shv[tid] = bet[tid] - m * sc;
    }
  }
  float a[4][4] = {{0,0,0,0},{0,0,0,0},{0,0,0,0},{0,0,0,0}};
  for (int c0 = 0; c0 < K; c0 += 64) {
    __syncthreads();
#pragma unroll
    for (int i = 0; i < 4; ++i) {
      const int idx = tid + i * 256;
      const int n = idx >> 4, c4 = (idx & 15) * 4;
      const int nn = min(n0 + n, N_NODES - 1);
      float4 v = *(const float4*)&in[(size_t)nn * K + c0 + c4];
      if (BN) {
        v.x = v.x * scv[c4] + shv[c4];
        v.y = v.y * scv[c4 + 1] + shv[c4 + 1];
        v.z = v.z * scv[c4 + 2] + shv[c4 + 2];
        v.w = v.w * scv[c4 + 3] + shv[c4 + 3];
      }
      *(float4*)&xs[n * 68 + c4] = v;
    }
#pragma unroll
    for (int i = 0; i < 4; ++i) {
      const int idx = tid + i * 256;
      const int c = idx >> 4, ch4 = (idx & 15) * 4;
      *(float4*)&wsm[c * 64 + ch4] = *(const float4*)&W[(size_t)(c0 + c) * 64 + ch4];
    }
    __syncthreads();
    for (int c = 0; c < 64; c += 4) {
      float wq[4][4];
#pragma unroll
      for (int cc = 0; cc < 4; ++cc) {
        const float4 w4 = *(const float4*)&wsm[(c + cc) * 64 + chb];
        wq[cc][0] = w4.x; wq[cc][1] = w4.y; wq[cc][2] = w4.z; wq[cc][3] = w4.w;
      }
#pragma unroll
      for (int i = 0; i < 4; ++i) {
        const float4 xv = *(const float4*)&xs[(nq + 16 * i) * 68 + c];
#pragma unroll
        for (int j = 0; j < 4; ++j) {
          a[i][j] = fmaf(xv.x, wq[0][j],
                    fmaf(xv.y, wq[1][j],
                    fmaf(xv.z, wq[2][j],
                    fmaf(xv.w, wq[3][j], a[i][j]))));
        }
      }
    }
  }
#pragma unroll
  for (int i = 0; i < 4; ++i) {
    const int n = n0 + nq + 16 * i;
    if (n < N_NODES) {
      const float d = dis[n];
      union { __half h[4]; float2 f; } u;
      u.h[0] = __float2half_rn(d * a[i][0]);
      u.h[1] = __float2half_rn(d * a[i][1]);
      u.h[2] = __float2half_rn(d * a[i][2]);
      u.h[3] = __float2half_rn(d * a[i][3]);
      *(float2*)&y[(size_t)n * 64 + chb] = u.f;
    }
  }
}

// ---------------- wide-load gather with wave-wide csr chunking ----------------
// R1 structure (16-edge strips, grid 2048) with ONE change: csr indices are loaded
// 64-at-a-time by the whole wave (lane l reads csr[e+l] -> one VMEM instr per 64
// edges, 8x fewer than per-strip loads) and distributed to strips via __shfl.
// This takes csr off the per-strip critical path: strip addresses come from
// register shuffles, so the 2-4 y-load pairs of a chunk issue back-to-back
// (deep MLP) without the in-order csr->y serialization R1 paid per strip.
// Lane layout: p = lane>>3 (edge slot 0..7), c8 = lane&7 (8 fp16 channels, float4).
// Butterfly unchanged: ch = c8*8 + 4p0 + 2p1 + p2 bijective over 64 lanes.
template <bool POOL>
__global__ __launch_bounds__(256) void k_gather(const int* __restrict__ csr,
                                                const int* __restrict__ rs,
                                                const __half* __restrict__ y,
                                                const float* __restrict__ dis,
                                                const float* __restrict__ bias,
                                                float* __restrict__ hout,
                                                float* __restrict__ stats,
                                                const int* __restrict__ batch,
                                                float* __restrict__ sums,
                                                float* __restrict__ cnt) {
  const int tid = threadIdx.x;
  const int lane = tid & 63;
  const int p = lane >> 3;        // edge slot 0..7 within a strip
  const int c8 = lane & 7;        // channel group: channels c8*8 .. c8*8+7
  const int ch = c8 * 8 + ((p & 1) << 2) + (p & 2) + ((p >> 2) & 1);
  const int wid = (blockIdx.x * 256 + tid) >> 6;
  const int nw = (gridDim.x * 256) >> 6;
  const int per = (N_NODES + nw - 1) / nw;
  const int n0 = wid * per;
  const int n1 = min(N_NODES, n0 + per);
  const float bch = bias[ch];
  float s1 = 0.f, s2 = 0.f;
  int curg = -1, run = 0;
  float px = 0.f;
  union U8 { float4 f4; __half2 h2[4]; };
  for (int n = n0; n < n1; ++n) {
    int e = rs[n];
    const int end = rs[n + 1];
    float acc[8] = {0.f, 0.f, 0.f, 0.f, 0.f, 0.f, 0.f, 0.f};
    if (p == 0) {  // self-loop term, counted once per channel by the p==0 slot
      U8 u;
      u.f4 = *(const float4*)&y[(size_t)n * 64 + c8 * 8];
#pragma unroll
      for (int k = 0; k < 4; ++k) {
        const float2 f = __half22float2(u.h2[k]);
        acc[2 * k] += f.x;
        acc[2 * k + 1] += f.y;
      }
    }
    while (e < end) {
      const int m = min(64, end - e);               // edges in this chunk (1..64)
      const int cidx = csr[(lane < m) ? e + lane : e];  // 1 VMEM instr = 64 indices
      int o = 0;
      for (; o + 16 <= m; o += 16) {                // full 16-edge strips
        const int i0 = __shfl(cidx, o + p);
        const int i1 = __shfl(cidx, o + 8 + p);
        U8 u0, u1;
        u0.f4 = *(const float4*)&y[(size_t)i0 * 64 + c8 * 8];
        u1.f4 = *(const float4*)&y[(size_t)i1 * 64 + c8 * 8];
#pragma unroll
        for (int k = 0; k < 4; ++k) {
          const float2 f0 = __half22float2(u0.h2[k]);
          const float2 f1 = __half22float2(u1.h2[k]);
          acc[2 * k] += f0.x + f1.x;
          acc[2 * k + 1] += f0.y + f1.y;
        }
      }
      if (o + 8 <= m) {                             // one 8-edge strip
        const int i0 = __shfl(cidx, o + p);
        U8 u0;
        u0.f4 = *(const float4*)&y[(size_t)i0 * 64 + c8 * 8];
#pragma unroll
        for (int k = 0; k < 4; ++k) {
          const float2 f0 = __half22float2(u0.h2[k]);
          acc[2 * k] += f0.x;
          acc[2 * k + 1] += f0.y;
        }
        o += 8;
      }
      if (o < m) {                                  // 1..7 leftover, masked by slot
        const int rem = m - o;
        const int i0 = __shfl(cidx, o + ((p < rem) ? p : 0));
        U8 u;
        u.f4 = *(const float4*)&y[(size_t)i0 * 64 + c8 * 8];
        if (p < rem) {
#pragma unroll
          for (int k = 0; k < 4; ++k) {
            const float2 f = __half22float2(u.h2[k]);
            acc[2 * k] += f.x;
            acc[2 * k + 1] += f.y;
          }
        }
      }
      e += m;
    }
    // recursive-halving butterfly across the 8 edge slots: 7 shuffles, 7 adds
    float t[4];
#pragma unroll
    for (int j = 0; j < 4; ++j) {
      const float send = (p & 1) ? acc[j] : acc[4 + j];
      const float keep = (p & 1) ? acc[4 + j] : acc[j];
      t[j] = keep + __shfl_xor(send, 8);
    }
    float u2v[2];
#pragma unroll
    for (int j = 0; j < 2; ++j) {
      const float send = (p & 2) ? t[j] : t[2 + j];
      const float keep = (p & 2) ? t[2 + j] : t[j];
      u2v[j] = keep + __shfl_xor(send, 16);
    }
    const float send3 = (p & 4) ? u2v[0] : u2v[1];
    const float keep3 = (p & 4) ? u2v[1] : u2v[0];
    const float s = keep3 + __shfl_xor(send3, 32);
    // s = full sum for channel `ch` of node n
    const float v = fmaxf(dis[n] * s + bch, 0.f);
    if (!POOL) hout[(size_t)n * 64 + ch] = v;
    s1 += v;
    s2 += v * v;
    if (POOL) {
      const int g = batch[n];
      if (g != curg) {
        if (run) {
          atomicAdd(&sums[curg * 64 + ch], px);
          if (lane == 0) atomicAdd(&cnt[curg], (float)run);
        }
        curg = g; run = 0; px = 0.f;
      }
      px += v;
      ++run;
    }
  }
  if (POOL && run) {
    atomicAdd(&sums[curg * 64 + ch], px);
    if (lane == 0) atomicAdd(&cnt[curg], (float)run);
  }
  __shared__ float r1[256], r2[256];
  const int wv = tid >> 6;
  r1[wv * 64 + ch] = s1;
  r2[wv * 64 + ch] = s2;
  __syncthreads();
  if (tid < 64) {
    atomicAdd(&stats[tid], r1[tid] + r1[tid + 64] + r1[tid + 128] + r1[tid + 192]);
  } else if (tid < 128) {
    const int h = tid - 64;
    atomicAdd(&stats[64 + h], r2[h] + r2[h + 64] + r2[h + 128] + r2[h + 192]);
  }
}

// ---------------- fused BN2-affine + 5-layer MLP head, one block per graph ----------------
__global__ __launch_bounds__(128) void k_mlp(const float* __restrict__ sums,
                                             const float* __restrict__ cnt,
                                             const float* __restrict__ stats,
                                             const float* __restrict__ gam,
                                             const float* __restrict__ bet,
                                             const float* __restrict__ fw1, const float* __restrict__ fb1,
                                             const float* __restrict__ fw2, const float* __restrict__ fb2,
                                             const float* __restrict__ fw3, const float* __restrict__ fb3,
                                             const float* __restrict__ fw4, const float* __restrict__ fb4,
                                             const float* __restrict__ ow, const float* __restrict__ ob,
                                             float* __restrict__ out) {
  __shared__ float u0[128], u1[128];
  const int g = blockIdx.x, t = threadIdx.x;
  if (t < 64) {
    const float m = stats[t] * (1.0f / N_NODES);
    const float v = stats[64 + t] * (1.0f / N_NODES) - m * m;
    const float sc = rsqrtf(v + BN_EPS) * gam[t];
    const float sh = bet[t] - m * sc;
    u0[t] = (sums[g * 64 + t] / fmaxf(cnt[g], 1.0f)) * sc + sh;  // BN affine on pooled mean
  }
  __syncthreads();
  if (t < 128) {
    float a = fb1[t];
    for (int k = 0; k < 64; ++k) a = fmaf(u0[k], fw1[k * 128 + t], a);
    u1[t] = fmaxf(a, 0.f);
  }
  __syncthreads();
  if (t < 64) {
    float a = fb2[t];
    for (int k = 0; k < 128; ++k) a = fmaf(u1[k], fw2[k * 64 + t], a);
    u0[t] = fmaxf(a, 0.f);
  }
  __syncthreads();
  if (t < 32) {
    float a = fb3[t];
    for (int k = 0; k < 64; ++k) a = fmaf(u0[k], fw3[k * 32 + t], a);
    u1[t] = fmaxf(a, 0.f);
  }
  __syncthreads();
  if (t < 16) {
    float a = fb4[t];
    for (int k = 0; k < 32; ++k) a = fmaf(u1[k], fw4[k * 16 + t], a);
    u0[t] = fmaxf(a, 0.f);
  }
  __syncthreads();
  if (t < 2) {
    float a = ob[t];
    for (int k = 0; k < 16; ++k) a = fmaf(u0[k], ow[k * 2 + t], a);
    out[g * 2 + t] = a;
  }
}

extern "C" void kernel_launch(void* const* d_in, const int* in_sizes, int n_in,
                              void* d_out, int out_size, void* d_ws, size_t ws_size,
                              hipStream_t stream) {
  const float* x    = (const float*)d_in[0];
  const int*   ei   = (const int*)d_in[1];
  const int*   batch= (const int*)d_in[2];
  const float* w1   = (const float*)d_in[3];
  const float* b1   = (const float*)d_in[4];
  const float* w2   = (const float*)d_in[5];
  const float* b2   = (const float*)d_in[6];
  const float* g1   = (const float*)d_in[7];
  const float* be1  = (const float*)d_in[8];
  const float* g2   = (const float*)d_in[9];
  const float* be2  = (const float*)d_in[10];
  const float* fw1  = (const float*)d_in[11]; const float* fb1 = (const float*)d_in[12];
  const float* fw2  = (const float*)d_in[13]; const float* fb2 = (const float*)d_in[14];
  const float* fw3  = (const float*)d_in[15]; const float* fb3 = (const float*)d_in[16];
  const float* fw4  = (const float*)d_in[17]; const float* fb4 = (const float*)d_in[18];
  const float* ow   = (const float*)d_in[19]; const float* ob  = (const float*)d_in[20];
  float* out = (float*)d_out;

  char* ws = (char*)d_ws;
  auto alloc = [&](size_t bytes) {
    void* p = ws;
    ws += (bytes + 255) & ~(size_t)255;
    return p;
  };
  float*  dis      = (float*)alloc((size_t)N_NODES * 4);
  int*    counts   = (int*)  alloc((size_t)NBUCK * NCHUNK * 4);
  int*    btot     = (int*)  alloc((size_t)NBUCK * 4);
  int*    bbase    = (int*)  alloc((size_t)(NBUCK + 1) * 4);
  int*    binned   = (int*)  alloc((size_t)E_EDGES * 4);
  int*    csr      = (int*)  alloc((size_t)E_EDGES * 4);
  int*    row_start= (int*)  alloc((size_t)(N_NODES + 1) * 4);
  __half* yH       = (__half*)alloc((size_t)N_NODES * 64 * 2);
  float*  hB       = (float*)alloc((size_t)N_NODES * 64 * 4);
  float*  stats1   = (float*)alloc(512);
  float*  stats2   = (float*)alloc(512);
  float*  sums     = (float*)alloc((size_t)NG * 64 * 4);
  float*  cnt      = (float*)alloc((size_t)NG * 4);

  const int nblkG = (N_NODES + 63) / 64;

  // zero accumulators; build node-sorted CSR via bucket binning (shared by both layers)
  k_zero    <<<128, 256, 0, stream>>>(stats1, stats2, sums, cnt);
  kb_hist   <<<NCHUNK, 256, 0, stream>>>(ei, counts);
  kb_scan1  <<<NBUCK, NCHUNK, 0, stream>>>(counts, btot);
  kb_scan2  <<<1, 1024, 0, stream>>>(btot, bbase);
  kb_scatter<<<NCHUNK, 256, 0, stream>>>(ei, counts, bbase, binned);
  kb_degsort<<<NBUCK, 256, 0, stream>>>(binned, bbase, csr, row_start, dis);

  // conv1: y1 = half(dis*(x@w1)) -> yH; gather(store) -> h1raw=hB + stats1
  k_gemm<256, false><<<nblkG, 256, 0, stream>>>(x, w1, dis, nullptr, nullptr, nullptr, yH);
  k_gather<false><<<2048, 256, 0, stream>>>(csr, row_start, yH, dis, b1, hB, stats1,
                                            nullptr, nullptr, nullptr);

  // conv2: y2 = half(dis*(BN1(h1raw)@w2)) -> yH; gather(pool) -> sums/cnt + stats2
  k_gemm<64, true><<<nblkG, 256, 0, stream>>>(hB, w2, dis, stats1, g1, be1, yH);
  k_gather<true><<<2048, 256, 0, stream>>>(csr, row_start, yH, dis, b2, nullptr, stats2,
                                           batch, sums, cnt);

  // BN2-affine on pooled means + MLP head
  k_mlp<<<NG, 128, 0, stream>>>(sums, cnt, stats2, g2, be2,
                                fw1, fb1, fw2, fb2, fw3, fb3, fw4, fb4, ow, ob, out);
}

// Round 8
// 555.492 us; speedup vs baseline: 2.8339x; 1.0155x over previous
//
#include <hip/hip_runtime.h>
#include <hip/hip_fp16.h>

#define N_NODES 100000
#define E_EDGES 3200000
#define NG      512
#define BN_EPS  1e-5f

#define BSH     7                 // 128 nodes per bucket
#define BNODES  128
#define NBUCK   782               // ceil(100000/128)
#define NCHUNK  1024
#define CHUNK   3125              // E_EDGES / NCHUNK

typedef _Float16 f16x8 __attribute__((ext_vector_type(8)));
typedef float    f32x4 __attribute__((ext_vector_type(4)));

// ---------------- zero stats / pool accumulators ----------------
__global__ __launch_bounds__(256) void k_zero(float* __restrict__ stats1,
                                              float* __restrict__ stats2,
                                              float* __restrict__ sums,
                                              float* __restrict__ cnt) {
  int i = blockIdx.x * 256 + threadIdx.x;
  if (i < 128) { stats1[i] = 0.f; stats2[i] = 0.f; }
  if (i < NG * 64) sums[i] = 0.f;
  if (i < NG) cnt[i] = 0.f;
}

// ---------------- per-chunk bucket histogram (LDS, no global atomics) ----------------
__global__ __launch_bounds__(256) void kb_hist(const int* __restrict__ ei,
                                               int* __restrict__ counts) {
  __shared__ int h[NBUCK];
  const int c = blockIdx.x, tid = threadIdx.x;
  for (int b = tid; b < NBUCK; b += 256) h[b] = 0;
  __syncthreads();
  const int* dst = ei + E_EDGES + c * CHUNK;
  for (int i = tid; i < CHUNK; i += 256) atomicAdd(&h[dst[i] >> BSH], 1);
  __syncthreads();
  for (int b = tid; b < NBUCK; b += 256) counts[b * NCHUNK + c] = h[b];
}

// ---------------- scan 1: within-bucket exclusive scan over chunks ----------------
__global__ __launch_bounds__(1024) void kb_scan1(int* __restrict__ counts,
                                                 int* __restrict__ btot) {
  __shared__ int sm[NCHUNK];
  const int b = blockIdx.x, tid = threadIdx.x;
  const int cval = counts[b * NCHUNK + tid];
  int val = cval;
  sm[tid] = val;
  __syncthreads();
  for (int off = 1; off < NCHUNK; off <<= 1) {
    int t = (tid >= off) ? sm[tid - off] : 0;
    __syncthreads();
    val += t;
    sm[tid] = val;
    __syncthreads();
  }
  counts[b * NCHUNK + tid] = val - cval;
  if (tid == NCHUNK - 1) btot[b] = val;
}

// ---------------- scan 2: exclusive scan of bucket totals ----------------
__global__ __launch_bounds__(1024) void kb_scan2(const int* __restrict__ btot,
                                                 int* __restrict__ bbase) {
  __shared__ int sm[1024];
  const int tid = threadIdx.x;
  const int cval = (tid < NBUCK) ? btot[tid] : 0;
  int val = cval;
  sm[tid] = val;
  __syncthreads();
  for (int off = 1; off < 1024; off <<= 1) {
    int t = (tid >= off) ? sm[tid - off] : 0;
    __syncthreads();
    val += t;
    sm[tid] = val;
    __syncthreads();
  }
  if (tid < NBUCK) bbase[tid] = val - cval;
  if (tid == NBUCK - 1) bbase[NBUCK] = val;  // == E_EDGES
}

// ---------------- partitioned scatter: pack (dstLocal<<17)|src into bucket runs ----------------
__global__ __launch_bounds__(256) void kb_scatter(const int* __restrict__ ei,
                                                  const int* __restrict__ counts,
                                                  const int* __restrict__ bbase,
                                                  int* __restrict__ binned) {
  __shared__ int cur[NBUCK];
  const int c = blockIdx.x, tid = threadIdx.x;
  for (int b = tid; b < NBUCK; b += 256) cur[b] = bbase[b] + counts[b * NCHUNK + c];
  __syncthreads();
  const int* srcp = ei + c * CHUNK;
  const int* dstp = ei + E_EDGES + c * CHUNK;
  for (int i = tid; i < CHUNK; i += 256) {
    const int s = srcp[i], d = dstp[i];
    const int pos = atomicAdd(&cur[d >> BSH], 1);
    binned[pos] = ((d & (BNODES - 1)) << 17) | s;
  }
}

// ---------------- per-bucket counting sort -> CSR + row_start + dis ----------------
__global__ __launch_bounds__(256) void kb_degsort(const int* __restrict__ binned,
                                                  const int* __restrict__ bbase,
                                                  int* __restrict__ csr,
                                                  int* __restrict__ row_start,
                                                  float* __restrict__ dis) {
  __shared__ int h[BNODES];    // counts, then cursors
  __shared__ int pre[BNODES];  // inclusive prefix
  const int b = blockIdx.x, tid = threadIdx.x;
  if (tid < BNODES) h[tid] = 0;
  __syncthreads();
  const int e0 = bbase[b], e1 = bbase[b + 1];
  for (int i = e0 + tid; i < e1; i += 256) atomicAdd(&h[binned[i] >> 17], 1);
  __syncthreads();
  if (tid < BNODES) pre[tid] = h[tid];
  __syncthreads();
  for (int off = 1; off < BNODES; off <<= 1) {
    int t = (tid >= off && tid < BNODES) ? pre[tid - off] : 0;
    __syncthreads();
    if (tid < BNODES) pre[tid] += t;
    __syncthreads();
  }
  if (tid < BNODES) {
    const int n = b * BNODES + tid;
    const int ex = e0 + pre[tid] - h[tid];  // exclusive start for this node
    if (n < N_NODES) {
      row_start[n] = ex;
      dis[n] = rsqrtf((float)(h[tid] + 1));  // +1 self loop
    }
    h[tid] = ex;  // cursor
  }
  if (b == NBUCK - 1 && tid == 0) row_start[N_NODES] = E_EDGES;
  __syncthreads();
  for (int i = e0 + tid; i < e1; i += 256) {
    const int v = binned[i];
    const int pos = atomicAdd(&h[v >> 17], 1);
    csr[pos] = v & 0x1FFFF;  // writes stay inside this bucket's ~16KB window
  }
}

// ---------------- W pre-split: W[256][64] fp32 -> wt_hi/wt_lo[64 ch][256 k] fp16 -----
// Transposed + hi/lo split once, so the MFMA gemm's B-fragments are contiguous
// ds_read_b128 loads. hi = rn(w); lo = rn(w - hi): combined ~2^-21 relative.
__global__ __launch_bounds__(256) void k_wsplit(const float* __restrict__ W,
                                                __half* __restrict__ wth,
                                                __half* __restrict__ wtl) {
  const int i = blockIdx.x * 256 + threadIdx.x;  // output index: ch*256 + k
  if (i < 64 * 256) {
    const int ch = i >> 8, k = i & 255;
    const float v = W[k * 64 + ch];
    const __half hi = __float2half_rn(v);
    wth[i] = hi;
    wtl[i] = __float2half_rn(v - __half2float(hi));
  }
}

// ---------------- conv1 GEMM via MFMA: y[n][ch] = half(dis[n]*(x@W1)[n][ch]) ---------
// Block = 256 thr = 4 waves; tile 64 nodes x 64 ch; K=256 in 4 chunks of 64.
// x is split to fp16 hi/lo in-kernel during LDS staging; W comes pre-split (k_wsplit).
// 3 MFMA passes per k-step (xh*wh + xh*wl + xl*wh) -> fp32 acc: error ~2^-21,
// comparable to the fp32-FMA path it replaces. Fragment mapping (m89/m92-verified):
// A row=lane&15, k=8*(lane>>4)+j (contiguous 8); B col=lane&15, same k; C col=lane&15,
// row=4*(lane>>4)+reg. Wave w owns nodes [w*16, w*16+16).
__global__ __launch_bounds__(256) void k_gemm1(const float* __restrict__ x,
                                               const __half* __restrict__ wth,
                                               const __half* __restrict__ wtl,
                                               const float* __restrict__ dis,
                                               __half* __restrict__ y) {
  __shared__ __half xh[64][72], xl[64][72];   // [node][k] (72: 16B-aligned rows)
  __shared__ __half wh[64][72], wl[64][72];   // [ch][k]
  const int tid = threadIdx.x;
  const int n0 = blockIdx.x * 64;
  const int w = tid >> 6, lane = tid & 63;
  const int l15 = lane & 15;
  const int kb = (lane >> 4) << 3;            // fragment k base (0,8,16,24)
  const int row4 = (lane >> 4) << 2;          // C row base
  f32x4 acc[4] = {{0.f,0.f,0.f,0.f},{0.f,0.f,0.f,0.f},
                  {0.f,0.f,0.f,0.f},{0.f,0.f,0.f,0.f}};
  for (int k0 = 0; k0 < 256; k0 += 64) {
    __syncthreads();
    // stage x tile [64 nodes][64 k] -> hi/lo fp16
#pragma unroll
    for (int i = 0; i < 4; ++i) {
      const int idx = tid + i * 256;
      const int n = idx >> 4, c4 = (idx & 15) * 4;
      const int nn = min(n0 + n, N_NODES - 1);
      const float4 v = *(const float4*)&x[(size_t)nn * 256 + k0 + c4];
      const __half h0 = __float2half_rn(v.x), h1 = __float2half_rn(v.y),
                   h2 = __float2half_rn(v.z), h3 = __float2half_rn(v.w);
      union { __half h[4]; float2 f; } uh = {{h0, h1, h2, h3}};
      *(float2*)&xh[n][c4] = uh.f;
      union { __half h[4]; float2 f; } ul = {{
          __float2half_rn(v.x - __half2float(h0)),
          __float2half_rn(v.y - __half2float(h1)),
          __float2half_rn(v.z - __half2float(h2)),
          __float2half_rn(v.w - __half2float(h3))}};
      *(float2*)&xl[n][c4] = ul.f;
    }
    // stage pre-split W tile [64 ch][64 k]
#pragma unroll
    for (int i = 0; i < 2; ++i) {
      const int idx = tid + i * 256;          // 512 slots = 64 ch x 8 k-octets
      const int ch = idx >> 3, k8 = (idx & 7) * 8;
      *(float4*)&wh[ch][k8] = *(const float4*)&wth[ch * 256 + k0 + k8];
      *(float4*)&wl[ch][k8] = *(const float4*)&wtl[ch * 256 + k0 + k8];
    }
    __syncthreads();
#pragma unroll
    for (int ks = 0; ks < 2; ++ks) {
      const int kk = ks * 32 + kb;
      const f16x8 ah = *(const f16x8*)&xh[w * 16 + l15][kk];
      const f16x8 al = *(const f16x8*)&xl[w * 16 + l15][kk];
#pragma unroll
      for (int t = 0; t < 4; ++t) {
        const f16x8 bh = *(const f16x8*)&wh[t * 16 + l15][kk];
        const f16x8 bl = *(const f16x8*)&wl[t * 16 + l15][kk];
        acc[t] = __builtin_amdgcn_mfma_f32_16x16x32_f16(ah, bh, acc[t], 0, 0, 0);
        acc[t] = __builtin_amdgcn_mfma_f32_16x16x32_f16(ah, bl, acc[t], 0, 0, 0);
        acc[t] = __builtin_amdgcn_mfma_f32_16x16x32_f16(al, bh, acc[t], 0, 0, 0);
      }
    }
  }
#pragma unroll
  for (int j = 0; j < 4; ++j) {
    const int n = n0 + w * 16 + row4 + j;
    if (n < N_NODES) {
      const float d = dis[n];
#pragma unroll
      for (int t = 0; t < 4; ++t) {
        y[(size_t)n * 64 + t * 16 + l15] = __float2half_rn(d * acc[t][j]);
      }
    }
  }
}

// ---------------- GEMM (vector): y[n][h] = half(dis[n] * sum_c in'[n][c]*W[c][h]) ----
template <int K, bool BN>
__global__ __launch_bounds__(256) void k_gemm(const float* __restrict__ in,
                                              const float* __restrict__ W,
                                              const float* __restrict__ dis,
                                              const float* __restrict__ stats,
                                              const float* __restrict__ gam,
                                              const float* __restrict__ bet,
                                              __half* __restrict__ y) {
  __shared__ float xs[64 * 68];   // [n][c] padded (stride 68)
  __shared__ float wsm[64 * 64];  // [c][ch]
  __shared__ float scv[64], shv[64];
  const int tid = threadIdx.x;
  const int n0 = blockIdx.x * 64;
  const int lane = tid & 63, wv = tid >> 6;
  const int nq = lane & 15;
  const int chb = wv * 16 + (lane >> 4) * 4;
  if (BN) {
    if (tid < 64) {
      const float m = stats[tid] * (1.0f / N_NODES);
      const float v = stats[64 + tid] * (1.0f / N_NODES) - m * m;
      const float sc = rsqrtf(v + BN_EPS) * gam[tid];
      scv[tid] = sc;
      shv[tid] = bet[tid] - m * sc;
    }
  }
  float a[4][4] = {{0,0,0,0},{0,0,0,0},{0,0,0,0},{0,0,0,0}};
  for (int c0 = 0; c0 < K; c0 += 64) {
    __syncthreads();
#pragma unroll
    for (int i = 0; i < 4; ++i) {
      const int idx = tid + i * 256;
      const int n = idx >> 4, c4 = (idx & 15) * 4;
      const int nn = min(n0 + n, N_NODES - 1);
      float4 v = *(const float4*)&in[(size_t)nn * K + c0 + c4];
      if (BN) {
        v.x = v.x * scv[c4] + shv[c4];
        v.y = v.y * scv[c4 + 1] + shv[c4 + 1];
        v.z = v.z * scv[c4 + 2] + shv[c4 + 2];
        v.w = v.w * scv[c4 + 3] + shv[c4 + 3];
      }
      *(float4*)&xs[n * 68 + c4] = v;
    }
#pragma unroll
    for (int i = 0; i < 4; ++i) {
      const int idx = tid + i * 256;
      const int c = idx >> 4, ch4 = (idx & 15) * 4;
      *(float4*)&wsm[c * 64 + ch4] = *(const float4*)&W[(size_t)(c0 + c) * 64 + ch4];
    }
    __syncthreads();
    for (int c = 0; c < 64; c += 4) {
      float wq[4][4];
#pragma unroll
      for (int cc = 0; cc < 4; ++cc) {
        const float4 w4 = *(const float4*)&wsm[(c + cc) * 64 + chb];
        wq[cc][0] = w4.x; wq[cc][1] = w4.y; wq[cc][2] = w4.z; wq[cc][3] = w4.w;
      }
#pragma unroll
      for (int i = 0; i < 4; ++i) {
        const float4 xv = *(const float4*)&xs[(nq + 16 * i) * 68 + c];
#pragma unroll
        for (int j = 0; j < 4; ++j) {
          a[i][j] = fmaf(xv.x, wq[0][j],
                    fmaf(xv.y, wq[1][j],
                    fmaf(xv.z, wq[2][j],
                    fmaf(xv.w, wq[3][j], a[i][j]))));
        }
      }
    }
  }
#pragma unroll
  for (int i = 0; i < 4; ++i) {
    const int n = n0 + nq + 16 * i;
    if (n < N_NODES) {
      const float d = dis[n];
      union { __half h[4]; float2 f; } u;
      u.h[0] = __float2half_rn(d * a[i][0]);
      u.h[1] = __float2half_rn(d * a[i][1]);
      u.h[2] = __float2half_rn(d * a[i][2]);
      u.h[3] = __float2half_rn(d * a[i][3]);
      *(float2*)&y[(size_t)n * 64 + chb] = u.f;
    }
  }
}

// ---------------- wide-load gather with wave-wide csr chunking (R7, verified) --------
template <bool POOL>
__global__ __launch_bounds__(256) void k_gather(const int* __restrict__ csr,
                                                const int* __restrict__ rs,
                                                const __half* __restrict__ y,
                                                const float* __restrict__ dis,
                                                const float* __restrict__ bias,
                                                float* __restrict__ hout,
                                                float* __restrict__ stats,
                                                const int* __restrict__ batch,
                                                float* __restrict__ sums,
                                                float* __restrict__ cnt) {
  const int tid = threadIdx.x;
  const int lane = tid & 63;
  const int p = lane >> 3;        // edge slot 0..7 within a strip
  const int c8 = lane & 7;        // channel group: channels c8*8 .. c8*8+7
  const int ch = c8 * 8 + ((p & 1) << 2) + (p & 2) + ((p >> 2) & 1);
  const int wid = (blockIdx.x * 256 + tid) >> 6;
  const int nw = (gridDim.x * 256) >> 6;
  const int per = (N_NODES + nw - 1) / nw;
  const int n0 = wid * per;
  const int n1 = min(N_NODES, n0 + per);
  const float bch = bias[ch];
  float s1 = 0.f, s2 = 0.f;
  int curg = -1, run = 0;
  float px = 0.f;
  union U8 { float4 f4; __half2 h2[4]; };
  for (int n = n0; n < n1; ++n) {
    int e = rs[n];
    const int end = rs[n + 1];
    float acc[8] = {0.f, 0.f, 0.f, 0.f, 0.f, 0.f, 0.f, 0.f};
    if (p == 0) {  // self-loop term, counted once per channel by the p==0 slot
      U8 u;
      u.f4 = *(const float4*)&y[(size_t)n * 64 + c8 * 8];
#pragma unroll
      for (int k = 0; k < 4; ++k) {
        const float2 f = __half22float2(u.h2[k]);
        acc[2 * k] += f.x;
        acc[2 * k + 1] += f.y;
      }
    }
    while (e < end) {
      const int m = min(64, end - e);               // edges in this chunk (1..64)
      const int cidx = csr[(lane < m) ? e + lane : e];  // 1 VMEM instr = 64 indices
      int o = 0;
      for (; o + 16 <= m; o += 16) {                // full 16-edge strips
        const int i0 = __shfl(cidx, o + p);
        const int i1 = __shfl(cidx, o + 8 + p);
        U8 u0, u1;
        u0.f4 = *(const float4*)&y[(size_t)i0 * 64 + c8 * 8];
        u1.f4 = *(const float4*)&y[(size_t)i1 * 64 + c8 * 8];
#pragma unroll
        for (int k = 0; k < 4; ++k) {
          const float2 f0 = __half22float2(u0.h2[k]);
          const float2 f1 = __half22float2(u1.h2[k]);
          acc[2 * k] += f0.x + f1.x;
          acc[2 * k + 1] += f0.y + f1.y;
        }
      }
      if (o + 8 <= m) {                             // one 8-edge strip
        const int i0 = __shfl(cidx, o + p);
        U8 u0;
        u0.f4 = *(const float4*)&y[(size_t)i0 * 64 + c8 * 8];
#pragma unroll
        for (int k = 0; k < 4; ++k) {
          const float2 f0 = __half22float2(u0.h2[k]);
          acc[2 * k] += f0.x;
          acc[2 * k + 1] += f0.y;
        }
        o += 8;
      }
      if (o < m) {                                  // 1..7 leftover, masked by slot
        const int rem = m - o;
        const int i0 = __shfl(cidx, o + ((p < rem) ? p : 0));
        U8 u;
        u.f4 = *(const float4*)&y[(size_t)i0 * 64 + c8 * 8];
        if (p < rem) {
#pragma unroll
          for (int k = 0; k < 4; ++k) {
            const float2 f = __half22float2(u.h2[k]);
            acc[2 * k] += f.x;
            acc[2 * k + 1] += f.y;
          }
        }
      }
      e += m;
    }
    // recursive-halving butterfly across the 8 edge slots: 7 shuffles, 7 adds
    float t[4];
#pragma unroll
    for (int j = 0; j < 4; ++j) {
      const float send = (p & 1) ? acc[j] : acc[4 + j];
      const float keep = (p & 1) ? acc[4 + j] : acc[j];
      t[j] = keep + __shfl_xor(send, 8);
    }
    float u2v[2];
#pragma unroll
    for (int j = 0; j < 2; ++j) {
      const float send = (p & 2) ? t[j] : t[2 + j];
      const float keep = (p & 2) ? t[2 + j] : t[j];
      u2v[j] = keep + __shfl_xor(send, 16);
    }
    const float send3 = (p & 4) ? u2v[0] : u2v[1];
    const float keep3 = (p & 4) ? u2v[1] : u2v[0];
    const float s = keep3 + __shfl_xor(send3, 32);
    // s = full sum for channel `ch` of node n
    const float v = fmaxf(dis[n] * s + bch, 0.f);
    if (!POOL) hout[(size_t)n * 64 + ch] = v;
    s1 += v;
    s2 += v * v;
    if (POOL) {
      const int g = batch[n];
      if (g != curg) {
        if (run) {
          atomicAdd(&sums[curg * 64 + ch], px);
          if (lane == 0) atomicAdd(&cnt[curg], (float)run);
        }
        curg = g; run = 0; px = 0.f;
      }
      px += v;
      ++run;
    }
  }
  if (POOL && run) {
    atomicAdd(&sums[curg * 64 + ch], px);
    if (lane == 0) atomicAdd(&cnt[curg], (float)run);
  }
  __shared__ float r1[256], r2[256];
  const int wv = tid >> 6;
  r1[wv * 64 + ch] = s1;
  r2[wv * 64 + ch] = s2;
  __syncthreads();
  if (tid < 64) {
    atomicAdd(&stats[tid], r1[tid] + r1[tid + 64] + r1[tid + 128] + r1[tid + 192]);
  } else if (tid < 128) {
    const int h = tid - 64;
    atomicAdd(&stats[64 + h], r2[h] + r2[h + 64] + r2[h + 128] + r2[h + 192]);
  }
}

// ---------------- fused BN2-affine + 5-layer MLP head, one block per graph ----------------
__global__ __launch_bounds__(128) void k_mlp(const float* __restrict__ sums,
                                             const float* __restrict__ cnt,
                                             const float* __restrict__ stats,
                                             const float* __restrict__ gam,
                                             const float* __restrict__ bet,
                                             const float* __restrict__ fw1, const float* __restrict__ fb1,
                                             const float* __restrict__ fw2, const float* __restrict__ fb2,
                                             const float* __restrict__ fw3, const float* __restrict__ fb3,
                                             const float* __restrict__ fw4, const float* __restrict__ fb4,
                                             const float* __restrict__ ow, const float* __restrict__ ob,
                                             float* __restrict__ out) {
  __shared__ float u0[128], u1[128];
  const int g = blockIdx.x, t = threadIdx.x;
  if (t < 64) {
    const float m = stats[t] * (1.0f / N_NODES);
    const float v = stats[64 + t] * (1.0f / N_NODES) - m * m;
    const float sc = rsqrtf(v + BN_EPS) * gam[t];
    const float sh = bet[t] - m * sc;
    u0[t] = (sums[g * 64 + t] / fmaxf(cnt[g], 1.0f)) * sc + sh;  // BN affine on pooled mean
  }
  __syncthreads();
  if (t < 128) {
    float a = fb1[t];
    for (int k = 0; k < 64; ++k) a = fmaf(u0[k], fw1[k * 128 + t], a);
    u1[t] = fmaxf(a, 0.f);
  }
  __syncthreads();
  if (t < 64) {
    float a = fb2[t];
    for (int k = 0; k < 128; ++k) a = fmaf(u1[k], fw2[k * 64 + t], a);
    u0[t] = fmaxf(a, 0.f);
  }
  __syncthreads();
  if (t < 32) {
    float a = fb3[t];
    for (int k = 0; k < 64; ++k) a = fmaf(u0[k], fw3[k * 32 + t], a);
    u1[t] = fmaxf(a, 0.f);
  }
  __syncthreads();
  if (t < 16) {
    float a = fb4[t];
    for (int k = 0; k < 32; ++k) a = fmaf(u1[k], fw4[k * 16 + t], a);
    u0[t] = fmaxf(a, 0.f);
  }
  __syncthreads();
  if (t < 2) {
    float a = ob[t];
    for (int k = 0; k < 16; ++k) a = fmaf(u0[k], ow[k * 2 + t], a);
    out[g * 2 + t] = a;
  }
}

extern "C" void kernel_launch(void* const* d_in, const int* in_sizes, int n_in,
                              void* d_out, int out_size, void* d_ws, size_t ws_size,
                              hipStream_t stream) {
  const float* x    = (const float*)d_in[0];
  const int*   ei   = (const int*)d_in[1];
  const int*   batch= (const int*)d_in[2];
  const float* w1   = (const float*)d_in[3];
  const float* b1   = (const float*)d_in[4];
  const float* w2   = (const float*)d_in[5];
  const float* b2   = (const float*)d_in[6];
  const float* g1   = (const float*)d_in[7];
  const float* be1  = (const float*)d_in[8];
  const float* g2   = (const float*)d_in[9];
  const float* be2  = (const float*)d_in[10];
  const float* fw1  = (const float*)d_in[11]; const float* fb1 = (const float*)d_in[12];
  const float* fw2  = (const float*)d_in[13]; const float* fb2 = (const float*)d_in[14];
  const float* fw3  = (const float*)d_in[15]; const float* fb3 = (const float*)d_in[16];
  const float* fw4  = (const float*)d_in[17]; const float* fb4 = (const float*)d_in[18];
  const float* ow   = (const float*)d_in[19]; const float* ob  = (const float*)d_in[20];
  float* out = (float*)d_out;

  char* ws = (char*)d_ws;
  auto alloc = [&](size_t bytes) {
    void* p = ws;
    ws += (bytes + 255) & ~(size_t)255;
    return p;
  };
  float*  dis      = (float*)alloc((size_t)N_NODES * 4);
  int*    counts   = (int*)  alloc((size_t)NBUCK * NCHUNK * 4);
  int*    btot     = (int*)  alloc((size_t)NBUCK * 4);
  int*    bbase    = (int*)  alloc((size_t)(NBUCK + 1) * 4);
  int*    binned   = (int*)  alloc((size_t)E_EDGES * 4);
  int*    csr      = (int*)  alloc((size_t)E_EDGES * 4);
  int*    row_start= (int*)  alloc((size_t)(N_NODES + 1) * 4);
  __half* yH       = (__half*)alloc((size_t)N_NODES * 64 * 2);
  float*  hB       = (float*)alloc((size_t)N_NODES * 64 * 4);
  float*  stats1   = (float*)alloc(512);
  float*  stats2   = (float*)alloc(512);
  float*  sums     = (float*)alloc((size_t)NG * 64 * 4);
  float*  cnt      = (float*)alloc((size_t)NG * 4);
  __half* wth      = (__half*)alloc((size_t)64 * 256 * 2);
  __half* wtl      = (__half*)alloc((size_t)64 * 256 * 2);

  const int nblkG = (N_NODES + 63) / 64;

  // zero accumulators; build node-sorted CSR via bucket binning (shared by both layers)
  k_zero    <<<128, 256, 0, stream>>>(stats1, stats2, sums, cnt);
  k_wsplit  <<<64, 256, 0, stream>>>(w1, wth, wtl);
  kb_hist   <<<NCHUNK, 256, 0, stream>>>(ei, counts);
  kb_scan1  <<<NBUCK, NCHUNK, 0, stream>>>(counts, btot);
  kb_scan2  <<<1, 1024, 0, stream>>>(btot, bbase);
  kb_scatter<<<NCHUNK, 256, 0, stream>>>(ei, counts, bbase, binned);
  kb_degsort<<<NBUCK, 256, 0, stream>>>(binned, bbase, csr, row_start, dis);

  // conv1: y1 = half(dis*(x@w1)) via MFMA (split fp16) -> yH; gather(store) -> hB + stats1
  k_gemm1<<<nblkG, 256, 0, stream>>>(x, wth, wtl, dis, yH);
  k_gather<false><<<2048, 256, 0, stream>>>(csr, row_start, yH, dis, b1, hB, stats1,
                                            nullptr, nullptr, nullptr);

  // conv2: y2 = half(dis*(BN1(h1raw)@w2)) -> yH; gather(pool) -> sums/cnt + stats2
  k_gemm<64, true><<<nblkG, 256, 0, stream>>>(hB, w2, dis, stats1, g1, be1, yH);
  k_gather<true><<<2048, 256, 0, stream>>>(csr, row_start, yH, dis, b2, nullptr, stats2,
                                           batch, sums, cnt);

  // BN2-affine on pooled means + MLP head
  k_mlp<<<NG, 128, 0, stream>>>(sums, cnt, stats2, g2, be2,
                                fw1, fb1, fw2, fb2, fw3, fb3, fw4, fb4, ow, ob, out);
}